// Round 7
// baseline (883.554 us; speedup 1.0000x reference)
//
#include <hip/hip_runtime.h>
#include <hip/hip_bf16.h>

// Problem constants (reference: B=1024, F=128, E=256, HEAD_NUM=8, d=32)
// Reference dtypes: ALL fp32 (inputs and output). bf16 internally.
#define B_SZ 1024
#define F_SZ 128
#define E_SZ 256
#define H_NUM 8
#define D_SZ 32

typedef __bf16 bf16x8 __attribute__((ext_vector_type(8)));
typedef float f32x4 __attribute__((ext_vector_type(4)));
typedef unsigned short u16x4 __attribute__((ext_vector_type(4)));

__device__ __forceinline__ bf16x8 frag_at(const __hip_bfloat16* p) {
  return *reinterpret_cast<const bf16x8*>(p);
}

// load 8 consecutive fp32 and round to a bf16x8 MFMA fragment
__device__ __forceinline__ bf16x8 cvt_frag(const float* p) {
  float4 a = *reinterpret_cast<const float4*>(p);
  float4 b = *reinterpret_cast<const float4*>(p + 4);
  bf16x8 r;
  r[0] = (__bf16)a.x; r[1] = (__bf16)a.y; r[2] = (__bf16)a.z; r[3] = (__bf16)a.w;
  r[4] = (__bf16)b.x; r[5] = (__bf16)b.y; r[6] = (__bf16)b.z; r[7] = (__bf16)b.w;
  return r;
}

// ---------------------------------------------------------------------------
// Prep: transpose the four fp32 E x E weights into bf16 WT[n][e] (n-major),
// so MFMA B-fragments (8 k-contiguous elems per output column) are 16B loads.
// ---------------------------------------------------------------------------
__global__ void transpose_weights(const float* __restrict__ W0,
                                  const float* __restrict__ W1,
                                  const float* __restrict__ W2,
                                  const float* __restrict__ W3,
                                  __hip_bfloat16* __restrict__ WT) {
  __shared__ float tile[64][65];
  const int wsel = blockIdx.x >> 4;
  const float* W = wsel == 0 ? W0 : wsel == 1 ? W1 : wsel == 2 ? W2 : W3;
  __hip_bfloat16* T = WT + wsel * (E_SZ * E_SZ);
  const int t = blockIdx.x & 15;
  const int tr = (t >> 2) * 64, tc = (t & 3) * 64;
  for (int k = 0; k < 16; ++k) {
    int fl = k * 256 + threadIdx.x;
    int lr = fl >> 6, lc = fl & 63;
    tile[lr][lc] = W[(tr + lr) * E_SZ + tc + lc];
  }
  __syncthreads();
  for (int k = 0; k < 16; ++k) {
    int fl = k * 256 + threadIdx.x;
    int lr = fl >> 6, lc = fl & 63;
    T[(tc + lr) * E_SZ + tr + lc] = __float2bfloat16(tile[lc][lr]);
  }
}

// ---------------------------------------------------------------------------
// Kernel A: QKVR projection GEMM. ZERO LDS, ZERO barriers.
// Grid 8192 = 1024 m-blocks (one batch b each, BM=128=F) x 8 n-blocks
// (BN=128; mat = ntb>>1 since each weight has 256 cols). 512 thr = 8 waves
// in a 2(m) x 4(n) grid; wave tile 64 rows x 32 cols = 4x2 C-tiles.
// A-frags: X fp32 from global (L1/L2 reuse), converted to bf16 in regs.
// B-frags: 16B loads from L2-resident WT.
// Outputs: Qo/Ko/Ro row-major bf16 [131072][256]; V written TRANSPOSED as
// VT[b][h][d][f] bf16 so the attention kernel reads PV B-frags as 16B loads.
// ---------------------------------------------------------------------------
__global__ __launch_bounds__(512, 1)
void gemm_qkvr(const float* __restrict__ X,
               const __hip_bfloat16* __restrict__ WT,
               __hip_bfloat16* __restrict__ Qo,
               __hip_bfloat16* __restrict__ Ko,
               __hip_bfloat16* __restrict__ Ro,
               __hip_bfloat16* __restrict__ VT) {
  const int tid  = threadIdx.x;
  const int wave = tid >> 6;
  const int lane = tid & 63;
  const int quad = lane >> 4;
  const int l16  = lane & 15;
  const int wm   = wave >> 2;            // 0..1 : row half
  const int wn   = wave & 3;             // 0..3 : col quarter
  const int bm   = blockIdx.x >> 3;      // batch element b
  const int ntb  = blockIdx.x & 7;       // n-block
  const int mat  = ntb >> 1;             // 0=Q 1=K 2=V 3=R
  const int col0 = (ntb & 1) * 128 + wn * 32;  // col within mat, this wave
  const float* Xb = X + (size_t)bm * (F_SZ * E_SZ);
  const __hip_bfloat16* Wb = WT + mat * (E_SZ * E_SZ);

  f32x4 acc[4][2];
  #pragma unroll
  for (int mt = 0; mt < 4; ++mt)
    #pragma unroll
    for (int nt = 0; nt < 2; ++nt) acc[mt][nt] = f32x4{0.f, 0.f, 0.f, 0.f};

  #pragma unroll 2
  for (int kit = 0; kit < 4; ++kit) {
    #pragma unroll
    for (int kk = 0; kk < 2; ++kk) {
      const int kb = kit * 64 + kk * 32 + quad * 8;
      bf16x8 b0 = frag_at(Wb + (col0 + l16) * E_SZ + kb);
      bf16x8 b1 = frag_at(Wb + (col0 + 16 + l16) * E_SZ + kb);
      #pragma unroll
      for (int mt = 0; mt < 4; ++mt) {
        bf16x8 a = cvt_frag(Xb + (wm * 64 + mt * 16 + l16) * E_SZ + kb);
        acc[mt][0] = __builtin_amdgcn_mfma_f32_16x16x32_bf16(a, b0, acc[mt][0], 0, 0, 0);
        acc[mt][1] = __builtin_amdgcn_mfma_f32_16x16x32_bf16(a, b1, acc[mt][1], 0, 0, 0);
      }
    }
  }

  // ---- epilogue: C/D layout row = quad*4+reg, col = l16
  if (mat != 2) {
    __hip_bfloat16* O = (mat == 0) ? Qo : (mat == 1) ? Ko : Ro;
    #pragma unroll
    for (int mt = 0; mt < 4; ++mt)
      #pragma unroll
      for (int nt = 0; nt < 2; ++nt)
        #pragma unroll
        for (int reg = 0; reg < 4; ++reg) {
          size_t m = (size_t)bm * F_SZ + wm * 64 + mt * 16 + quad * 4 + reg;
          O[m * E_SZ + col0 + nt * 16 + l16] = __float2bfloat16(acc[mt][nt][reg]);
        }
  } else {
    const int h = col0 >> 5;             // head (uniform per wave)
    #pragma unroll
    for (int mt = 0; mt < 4; ++mt)
      #pragma unroll
      for (int nt = 0; nt < 2; ++nt) {
        const int d  = nt * 16 + l16;
        const int f0 = wm * 64 + mt * 16 + quad * 4;
        u16x4 pk;
        #pragma unroll
        for (int reg = 0; reg < 4; ++reg) {
          __hip_bfloat16 bv = __float2bfloat16(acc[mt][nt][reg]);
          pk[reg] = *reinterpret_cast<unsigned short*>(&bv);
        }
        *reinterpret_cast<u16x4*>(
            VT + (((size_t)bm * H_NUM + h) * D_SZ + d) * F_SZ + f0) = pk;
      }
  }
}

// ---------------------------------------------------------------------------
// Kernel B: attention. One block per (b,h); 8192 blocks x 256 thr (4 waves).
// ZERO barriers: Q/K/VT fragments are direct 16B global loads (K/VT tiles are
// 8KB -> L1-hot); P goes through a WAVE-PRIVATE LDS slice (C-layout ->
// A-layout transform), so no cross-wave synchronization exists at all.
// Wave w owns f-rows 32w..32w+31 (2 m-tiles).
// ---------------------------------------------------------------------------
#define STRP2 144   // P row stride: 16B-aligned rows, 4-way bank aliasing max
__global__ __launch_bounds__(256, 1)
void attn(const __hip_bfloat16* __restrict__ Qo,
          const __hip_bfloat16* __restrict__ Ko,
          const __hip_bfloat16* __restrict__ Ro,
          const __hip_bfloat16* __restrict__ VT,
          float* __restrict__ out) {
  __shared__ __align__(16) __hip_bfloat16 Ps[4][32 * STRP2];  // 36864 B

  const int tid  = threadIdx.x;
  const int wave = tid >> 6;
  const int lane = tid & 63;
  const int quad = lane >> 4;
  const int l16  = lane & 15;
  const int b    = blockIdx.x >> 3;
  const int h    = blockIdx.x & 7;
  const size_t rowbase = (size_t)b * F_SZ;   // global row of f=0
  const int hcol = h * D_SZ;
  const int fw   = wave * 32;                // wave's first f row
  __hip_bfloat16* Pw = &Ps[wave][0];
  const __hip_bfloat16* VTh = VT + ((size_t)b * H_NUM + h) * (D_SZ * F_SZ);

  // ---- S = Q_h K_h^T (K=32 -> one MFMA per 16x16 tile)
  bf16x8 bk[8];
  #pragma unroll
  for (int nt = 0; nt < 8; ++nt)
    bk[nt] = frag_at(Ko + (rowbase + nt * 16 + l16) * E_SZ + hcol + quad * 8);

  f32x4 s[2][8];
  #pragma unroll
  for (int mt = 0; mt < 2; ++mt) {
    bf16x8 aq = frag_at(Qo + (rowbase + fw + mt * 16 + l16) * E_SZ + hcol + quad * 8);
    #pragma unroll
    for (int nt = 0; nt < 8; ++nt)
      s[mt][nt] = __builtin_amdgcn_mfma_f32_16x16x32_bf16(
          aq, bk[nt], f32x4{0.f, 0.f, 0.f, 0.f}, 0, 0, 0);
  }

  // ---- row softmax (rows live on 16-lane quad groups) + P -> own LDS slice
  #pragma unroll
  for (int mt = 0; mt < 2; ++mt)
    #pragma unroll
    for (int reg = 0; reg < 4; ++reg) {
      float m = s[mt][0][reg];
      #pragma unroll
      for (int nt = 1; nt < 8; ++nt) m = fmaxf(m, s[mt][nt][reg]);
      #pragma unroll
      for (int off = 8; off >= 1; off >>= 1) m = fmaxf(m, __shfl_xor(m, off));
      float sum = 0.f;
      #pragma unroll
      for (int nt = 0; nt < 8; ++nt) {
        float e = __expf(s[mt][nt][reg] - m);
        s[mt][nt][reg] = e;
        sum += e;
      }
      #pragma unroll
      for (int off = 8; off >= 1; off >>= 1) sum += __shfl_xor(sum, off);
      float inv = 1.f / sum;
      int r = mt * 16 + quad * 4 + reg;    // row within wave slice
      #pragma unroll
      for (int nt = 0; nt < 8; ++nt)
        Pw[r * STRP2 + nt * 16 + l16] = __float2bfloat16(s[mt][nt][reg] * inv);
    }
  // P write->read is same-wave: compiler inserts lgkmcnt waits; no barrier.

  // ---- O = P V (K=128 -> 4 k-steps); V^T B-frags direct from global
  f32x4 o[2][2];
  o[0][0] = f32x4{0.f,0.f,0.f,0.f}; o[0][1] = f32x4{0.f,0.f,0.f,0.f};
  o[1][0] = f32x4{0.f,0.f,0.f,0.f}; o[1][1] = f32x4{0.f,0.f,0.f,0.f};
  #pragma unroll
  for (int ks = 0; ks < 4; ++ks) {
    bf16x8 bv0 = frag_at(VTh + (l16) * F_SZ      + ks * 32 + quad * 8);
    bf16x8 bv1 = frag_at(VTh + (16 + l16) * F_SZ + ks * 32 + quad * 8);
    #pragma unroll
    for (int mt = 0; mt < 2; ++mt) {
      bf16x8 ap = *reinterpret_cast<const bf16x8*>(
          Pw + (mt * 16 + l16) * STRP2 + ks * 32 + quad * 8);
      o[mt][0] = __builtin_amdgcn_mfma_f32_16x16x32_bf16(ap, bv0, o[mt][0], 0, 0, 0);
      o[mt][1] = __builtin_amdgcn_mfma_f32_16x16x32_bf16(ap, bv1, o[mt][1], 0, 0, 0);
    }
  }

  // ---- epilogue: + residual, relu (NaN-propagating), fp32 store
  #pragma unroll
  for (int mt = 0; mt < 2; ++mt)
    #pragma unroll
    for (int nt = 0; nt < 2; ++nt)
      #pragma unroll
      for (int reg = 0; reg < 4; ++reg) {
        int f = fw + mt * 16 + quad * 4 + reg;
        size_t idx = (rowbase + f) * E_SZ + hcol + nt * 16 + l16;
        float v = o[mt][nt][reg] + (float)Ro[idx];
        out[idx] = (v < 0.f) ? 0.f : v;
      }
}

// ===========================================================================
// FALLBACK (ws_size too small for the split path): round-5 fused kernel.
// ===========================================================================
#define STRQ 40
#define STRP 136
#define STRW 132
__global__ __launch_bounds__(512, 1)
void fused_attn(const float* __restrict__ Xg_all,
                const __hip_bfloat16* __restrict__ WT,
                float* __restrict__ out) {
  __shared__ __align__(16) __hip_bfloat16 Qs[F_SZ * STRQ];
  __shared__ __align__(16) __hip_bfloat16 Ks[F_SZ * STRQ];
  __shared__ __align__(16) __hip_bfloat16 VTs[D_SZ * STRP];
  __shared__ __align__(16) __hip_bfloat16 PsWs[F_SZ * STRP];
  __hip_bfloat16* Ws = PsWs;
  __hip_bfloat16* Ps = PsWs;

  const int tid = threadIdx.x, wave = tid >> 6, lane = tid & 63;
  const int quad = lane >> 4, l16 = lane & 15, b = blockIdx.x;
  const float* Xg = Xg_all + (size_t)b * (F_SZ * E_SZ);
  const int fbase = wave * 16;

  bf16x8 xa[8];
  #pragma unroll
  for (int ks = 0; ks < 8; ++ks)
    xa[ks] = cvt_frag(Xg + (fbase + l16) * E_SZ + ks * 32 + quad * 8);

  #pragma unroll 1
  for (int h = 0; h < H_NUM; ++h) {
    f32x4 acc[8];
    #pragma unroll
    for (int nt = 0; nt < 8; ++nt) acc[nt] = f32x4{0.f, 0.f, 0.f, 0.f};
    #pragma unroll
    for (int half = 0; half < 2; ++half) {
      #pragma unroll
      for (int i = 0; i < 4; ++i) {
        int ch = i * 512 + tid;
        int c = ch >> 4, kc = ch & 15;
        int mat = c >> 5, cim = c & 31;
        const __hip_bfloat16* src = WT + mat * (E_SZ * E_SZ)
                                   + (h * D_SZ + cim) * E_SZ + half * 128 + kc * 8;
        *reinterpret_cast<uint4*>(&Ws[c * STRW + kc * 8]) =
            *reinterpret_cast<const uint4*>(src);
      }
      __syncthreads();
      #pragma unroll
      for (int ksl = 0; ksl < 4; ++ksl) {
        int ks = half * 4 + ksl;
        #pragma unroll
        for (int nt = 0; nt < 8; ++nt) {
          bf16x8 bw = frag_at(Ws + ((nt >> 1) * 32 + (nt & 1) * 16 + l16) * STRW
                              + ksl * 32 + quad * 8);
          acc[nt] = __builtin_amdgcn_mfma_f32_16x16x32_bf16(xa[ks], bw, acc[nt], 0, 0, 0);
        }
      }
      __syncthreads();
    }
    #pragma unroll
    for (int reg = 0; reg < 4; ++reg) {
      int f = fbase + quad * 4 + reg;
      Qs[f * STRQ + l16]         = __float2bfloat16(acc[0][reg]);
      Qs[f * STRQ + 16 + l16]    = __float2bfloat16(acc[1][reg]);
      Ks[f * STRQ + l16]         = __float2bfloat16(acc[2][reg]);
      Ks[f * STRQ + 16 + l16]    = __float2bfloat16(acc[3][reg]);
      VTs[l16 * STRP + f]        = __float2bfloat16(acc[4][reg]);
      VTs[(16 + l16) * STRP + f] = __float2bfloat16(acc[5][reg]);
    }
    float r0[4], r1[4];
    #pragma unroll
    for (int reg = 0; reg < 4; ++reg) { r0[reg] = acc[6][reg]; r1[reg] = acc[7][reg]; }
    __syncthreads();
    f32x4 s[8];
    {
      bf16x8 aq = frag_at(Qs + (fbase + l16) * STRQ + quad * 8);
      #pragma unroll
      for (int nt = 0; nt < 8; ++nt) {
        bf16x8 bkk = frag_at(Ks + (nt * 16 + l16) * STRQ + quad * 8);
        s[nt] = __builtin_amdgcn_mfma_f32_16x16x32_bf16(
            aq, bkk, f32x4{0.f, 0.f, 0.f, 0.f}, 0, 0, 0);
      }
    }
    #pragma unroll
    for (int reg = 0; reg < 4; ++reg) {
      float m = s[0][reg];
      #pragma unroll
      for (int nt = 1; nt < 8; ++nt) m = fmaxf(m, s[nt][reg]);
      #pragma unroll
      for (int off = 8; off >= 1; off >>= 1) m = fmaxf(m, __shfl_xor(m, off));
      float sum = 0.f;
      #pragma unroll
      for (int nt = 0; nt < 8; ++nt) {
        float e = __expf(s[nt][reg] - m); s[nt][reg] = e; sum += e;
      }
      #pragma unroll
      for (int off = 8; off >= 1; off >>= 1) sum += __shfl_xor(sum, off);
      float inv = 1.f / sum;
      int f = fbase + quad * 4 + reg;
      #pragma unroll
      for (int nt = 0; nt < 8; ++nt)
        Ps[f * STRP + nt * 16 + l16] = __float2bfloat16(s[nt][reg] * inv);
    }
    __syncthreads();
    f32x4 o0 = {0.f,0.f,0.f,0.f}, o1 = {0.f,0.f,0.f,0.f};
    #pragma unroll
    for (int ks = 0; ks < 4; ++ks) {
      bf16x8 ap  = frag_at(Ps + (fbase + l16) * STRP + ks * 32 + quad * 8);
      bf16x8 bv0 = frag_at(VTs + l16 * STRP        + ks * 32 + quad * 8);
      bf16x8 bv1 = frag_at(VTs + (16 + l16) * STRP + ks * 32 + quad * 8);
      o0 = __builtin_amdgcn_mfma_f32_16x16x32_bf16(ap, bv0, o0, 0, 0, 0);
      o1 = __builtin_amdgcn_mfma_f32_16x16x32_bf16(ap, bv1, o1, 0, 0, 0);
    }
    #pragma unroll
    for (int reg = 0; reg < 4; ++reg) {
      int f = fbase + quad * 4 + reg;
      float v0 = o0[reg] + r0[reg]; v0 = (v0 < 0.f) ? 0.f : v0;
      float v1 = o1[reg] + r1[reg]; v1 = (v1 < 0.f) ? 0.f : v1;
      size_t base = ((size_t)b * F_SZ + f) * E_SZ + h * D_SZ;
      out[base + l16]      = v0;
      out[base + 16 + l16] = v1;
    }
    __syncthreads();
  }
}

// ---------------------------------------------------------------------------
extern "C" void kernel_launch(void* const* d_in, const int* in_sizes, int n_in,
                              void* d_out, int out_size, void* d_ws, size_t ws_size,
                              hipStream_t stream) {
  const float* X  = (const float*)d_in[0];
  const float* Wq = (const float*)d_in[1];
  const float* Wk = (const float*)d_in[2];
  const float* Wv = (const float*)d_in[3];
  const float* Wr = (const float*)d_in[4];
  float* out = (float*)d_out;

  char* ws = (char*)d_ws;
  const size_t WT_BYTES  = (size_t)4 * E_SZ * E_SZ * 2;           // 512 KB
  const size_t MAT_BYTES = (size_t)B_SZ * F_SZ * E_SZ * 2;        // 64 MB
  const size_t NEEDED = WT_BYTES + 4 * MAT_BYTES;                 // ~256.5 MB

  __hip_bfloat16* WT = (__hip_bfloat16*)ws;

  (void)hipGetLastError();  // clear stale error state
  transpose_weights<<<64, 256, 0, stream>>>(Wq, Wk, Wv, Wr, WT);

  if (ws_size >= NEEDED) {
    __hip_bfloat16* Qo = (__hip_bfloat16*)(ws + WT_BYTES);
    __hip_bfloat16* Ko = (__hip_bfloat16*)(ws + WT_BYTES + MAT_BYTES);
    __hip_bfloat16* Ro = (__hip_bfloat16*)(ws + WT_BYTES + 2 * MAT_BYTES);
    __hip_bfloat16* VT = (__hip_bfloat16*)(ws + WT_BYTES + 3 * MAT_BYTES);
    gemm_qkvr<<<B_SZ * 8, 512, 0, stream>>>(X, WT, Qo, Ko, Ro, VT);
    attn<<<B_SZ * H_NUM, 256, 0, stream>>>(Qo, Ko, Ro, VT, out);
  } else {
    fused_attn<<<B_SZ, 512, 0, stream>>>(X, WT, out);
  }

  // Launch-failure exfiltration (no-op when launches succeed).
  hipError_t err = hipGetLastError();
  if (err != hipSuccess) {
    hipMemsetAsync(d_out, 0x7F, 1024, stream);
  }
}

// Round 8
// 609.371 us; speedup vs baseline: 1.4499x; 1.4499x over previous
//
#include <hip/hip_runtime.h>
#include <hip/hip_bf16.h>

// Problem constants (reference: B=1024, F=128, E=256, HEAD_NUM=8, d=32)
// Reference dtypes: ALL fp32 (inputs and output). bf16 internally.
#define B_SZ 1024
#define F_SZ 128
#define E_SZ 256
#define H_NUM 8
#define D_SZ 32

typedef __bf16 bf16x8 __attribute__((ext_vector_type(8)));
typedef float f32x4 __attribute__((ext_vector_type(4)));
typedef unsigned short u16x4 __attribute__((ext_vector_type(4)));

__device__ __forceinline__ bf16x8 frag_at(const __hip_bfloat16* p) {
  return *reinterpret_cast<const bf16x8*>(p);
}

__device__ __forceinline__ bf16x8 pack_bf16x8(float4 a, float4 b) {
  bf16x8 r;
  r[0] = (__bf16)a.x; r[1] = (__bf16)a.y; r[2] = (__bf16)a.z; r[3] = (__bf16)a.w;
  r[4] = (__bf16)b.x; r[5] = (__bf16)b.y; r[6] = (__bf16)b.z; r[7] = (__bf16)b.w;
  return r;
}

__device__ __forceinline__ bf16x8 cvt_frag(const float* p) {
  return pack_bf16x8(*reinterpret_cast<const float4*>(p),
                     *reinterpret_cast<const float4*>(p + 4));
}

// ---------------------------------------------------------------------------
// Prep: transpose the four fp32 E x E weights into bf16 WT[n][e] (n-major).
// ---------------------------------------------------------------------------
__global__ void transpose_weights(const float* __restrict__ W0,
                                  const float* __restrict__ W1,
                                  const float* __restrict__ W2,
                                  const float* __restrict__ W3,
                                  __hip_bfloat16* __restrict__ WT) {
  __shared__ float tile[64][65];
  const int wsel = blockIdx.x >> 4;
  const float* W = wsel == 0 ? W0 : wsel == 1 ? W1 : wsel == 2 ? W2 : W3;
  __hip_bfloat16* T = WT + wsel * (E_SZ * E_SZ);
  const int t = blockIdx.x & 15;
  const int tr = (t >> 2) * 64, tc = (t & 3) * 64;
  for (int k = 0; k < 16; ++k) {
    int fl = k * 256 + threadIdx.x;
    int lr = fl >> 6, lc = fl & 63;
    tile[lr][lc] = W[(tr + lr) * E_SZ + tc + lc];
  }
  __syncthreads();
  for (int k = 0; k < 16; ++k) {
    int fl = k * 256 + threadIdx.x;
    int lr = fl >> 6, lc = fl & 63;
    T[(tc + lr) * E_SZ + tr + lc] = __float2bfloat16(tile[lc][lr]);
  }
}

// ---------------------------------------------------------------------------
// Kernel A v2: LDS-tiled QKVR projection GEMM (ladder pattern, m93-style
// with VGPR prefetch double-buffer).
// Grid 8192 = 1024 batches x 8 n-blocks (mat = ntb>>1, 128-col half).
// Block: 256 thr = 4 waves in 2x2; wave tile 64x64 = 4x4 C-tiles.
// K=256 -> 4 iters of BK=64. Per iter: stage X-tile (fp32->bf16) + WT-tile
// into padded LDS; 16 ds_read_b128 + 32 MFMA per wave. Next iter's global
// loads are issued BEFORE compute so latency hides under MFMA.
// Outputs: Qo/Ko/Ro row-major bf16 [131072][256]; V transposed VT[b][h][d][f].
// ---------------------------------------------------------------------------
#define STRA 72   // LDS row stride (64 + 8): rows 144 B apart -> 2-way max
__global__ __launch_bounds__(256, 1)
void gemm_qkvr(const float* __restrict__ X,
               const __hip_bfloat16* __restrict__ WT,
               __hip_bfloat16* __restrict__ Qo,
               __hip_bfloat16* __restrict__ Ko,
               __hip_bfloat16* __restrict__ Ro,
               __hip_bfloat16* __restrict__ VT) {
  __shared__ __align__(16) __hip_bfloat16 As[128 * STRA];  // 18432 B
  __shared__ __align__(16) __hip_bfloat16 Bs[128 * STRA];  // 18432 B

  const int tid  = threadIdx.x;
  const int wave = tid >> 6;
  const int lane = tid & 63;
  const int quad = lane >> 4;
  const int l16  = lane & 15;
  const int wm   = wave >> 1;            // 0..1 row half of the wave grid
  const int wn   = wave & 1;             // 0..1 col half
  const int bm   = blockIdx.x >> 3;      // batch element b
  const int ntb  = blockIdx.x & 7;       // n-block
  const int mat  = ntb >> 1;             // 0=Q 1=K 2=V 3=R
  const int colbase = (ntb & 1) * 128;   // col offset within mat
  const float* Xb = X + (size_t)bm * (F_SZ * E_SZ);
  const __hip_bfloat16* Wb = WT + mat * (E_SZ * E_SZ) + colbase * E_SZ;

  // per-thread staging slice: 4 chunks of 8 elems; chunk ch=i*256+tid:
  // row r = ch>>3 (8 chunks/row), chunk-in-row c = ch&7.
  float4 la0[4], la1[4];
  uint4  lb[4];

  auto load_tiles = [&](int kt) {
    const int k0 = kt * 64;
    #pragma unroll
    for (int i = 0; i < 4; ++i) {
      int ch = i * 256 + tid;
      int r = ch >> 3, c = ch & 7;
      const float* sa = Xb + r * E_SZ + k0 + c * 8;
      la0[i] = *reinterpret_cast<const float4*>(sa);
      la1[i] = *reinterpret_cast<const float4*>(sa + 4);
      lb[i]  = *reinterpret_cast<const uint4*>(Wb + r * E_SZ + k0 + c * 8);
    }
  };
  auto write_tiles = [&]() {
    #pragma unroll
    for (int i = 0; i < 4; ++i) {
      int ch = i * 256 + tid;
      int r = ch >> 3, c = ch & 7;
      bf16x8 av = pack_bf16x8(la0[i], la1[i]);
      *reinterpret_cast<bf16x8*>(&As[r * STRA + c * 8]) = av;
      *reinterpret_cast<uint4*>(&Bs[r * STRA + c * 8]) = lb[i];
    }
  };

  f32x4 acc[4][4];
  #pragma unroll
  for (int mt = 0; mt < 4; ++mt)
    #pragma unroll
    for (int nt = 0; nt < 4; ++nt) acc[mt][nt] = f32x4{0.f, 0.f, 0.f, 0.f};

  load_tiles(0);
  #pragma unroll
  for (int kt = 0; kt < 4; ++kt) {
    write_tiles();
    __syncthreads();
    if (kt < 3) load_tiles(kt + 1);   // in flight during compute
    #pragma unroll
    for (int kk = 0; kk < 2; ++kk) {
      const int ko = kk * 32 + quad * 8;
      bf16x8 af[4], bfr[4];
      #pragma unroll
      for (int mt = 0; mt < 4; ++mt)
        af[mt] = frag_at(&As[(wm * 64 + mt * 16 + l16) * STRA + ko]);
      #pragma unroll
      for (int nt = 0; nt < 4; ++nt)
        bfr[nt] = frag_at(&Bs[(wn * 64 + nt * 16 + l16) * STRA + ko]);
      #pragma unroll
      for (int mt = 0; mt < 4; ++mt)
        #pragma unroll
        for (int nt = 0; nt < 4; ++nt)
          acc[mt][nt] = __builtin_amdgcn_mfma_f32_16x16x32_bf16(
              af[mt], bfr[nt], acc[mt][nt], 0, 0, 0);
    }
    __syncthreads();
  }

  // ---- epilogue: C/D layout row = quad*4+reg, col = l16
  if (mat != 2) {
    __hip_bfloat16* O = (mat == 0) ? Qo : (mat == 1) ? Ko : Ro;
    #pragma unroll
    for (int mt = 0; mt < 4; ++mt)
      #pragma unroll
      for (int nt = 0; nt < 4; ++nt) {
        const int col = colbase + wn * 64 + nt * 16 + l16;
        #pragma unroll
        for (int reg = 0; reg < 4; ++reg) {
          size_t m = (size_t)bm * F_SZ + wm * 64 + mt * 16 + quad * 4 + reg;
          O[m * E_SZ + col] = __float2bfloat16(acc[mt][nt][reg]);
        }
      }
  } else {
    #pragma unroll
    for (int mt = 0; mt < 4; ++mt)
      #pragma unroll
      for (int nt = 0; nt < 4; ++nt) {
        const int c = colbase + wn * 64 + nt * 16;   // multiple of 16
        const int h = (c + l16) >> 5;                // uniform per nt (c%32 in {0,16})
        const int d = (c + l16) & 31;
        const int f0 = wm * 64 + mt * 16 + quad * 4;
        u16x4 pk;
        #pragma unroll
        for (int reg = 0; reg < 4; ++reg) {
          __hip_bfloat16 bv = __float2bfloat16(acc[mt][nt][reg]);
          pk[reg] = *reinterpret_cast<unsigned short*>(&bv);
        }
        *reinterpret_cast<u16x4*>(
            VT + (((size_t)bm * H_NUM + h) * D_SZ + d) * F_SZ + f0) = pk;
      }
  }
}

// ---------------------------------------------------------------------------
// Kernel B: attention. One block per (b,h); 8192 blocks x 256 thr (4 waves).
// Zero barriers; P via wave-private LDS slice. (Unchanged from round 7;
// it measured ~250 us and becomes the next optimization target.)
// ---------------------------------------------------------------------------
#define STRP2 144
__global__ __launch_bounds__(256, 1)
void attn(const __hip_bfloat16* __restrict__ Qo,
          const __hip_bfloat16* __restrict__ Ko,
          const __hip_bfloat16* __restrict__ Ro,
          const __hip_bfloat16* __restrict__ VT,
          float* __restrict__ out) {
  __shared__ __align__(16) __hip_bfloat16 Ps[4][32 * STRP2];  // 36864 B

  const int tid  = threadIdx.x;
  const int wave = tid >> 6;
  const int lane = tid & 63;
  const int quad = lane >> 4;
  const int l16  = lane & 15;
  const int b    = blockIdx.x >> 3;
  const int h    = blockIdx.x & 7;
  const size_t rowbase = (size_t)b * F_SZ;
  const int hcol = h * D_SZ;
  const int fw   = wave * 32;
  __hip_bfloat16* Pw = &Ps[wave][0];
  const __hip_bfloat16* VTh = VT + ((size_t)b * H_NUM + h) * (D_SZ * F_SZ);

  // ---- S = Q_h K_h^T (K=32 -> one MFMA per 16x16 tile)
  bf16x8 bk[8];
  #pragma unroll
  for (int nt = 0; nt < 8; ++nt)
    bk[nt] = frag_at(Ko + (rowbase + nt * 16 + l16) * E_SZ + hcol + quad * 8);

  f32x4 s[2][8];
  #pragma unroll
  for (int mt = 0; mt < 2; ++mt) {
    bf16x8 aq = frag_at(Qo + (rowbase + fw + mt * 16 + l16) * E_SZ + hcol + quad * 8);
    #pragma unroll
    for (int nt = 0; nt < 8; ++nt)
      s[mt][nt] = __builtin_amdgcn_mfma_f32_16x16x32_bf16(
          aq, bk[nt], f32x4{0.f, 0.f, 0.f, 0.f}, 0, 0, 0);
  }

  // ---- row softmax + P -> own LDS slice (C-layout -> A-layout)
  #pragma unroll
  for (int mt = 0; mt < 2; ++mt)
    #pragma unroll
    for (int reg = 0; reg < 4; ++reg) {
      float m = s[mt][0][reg];
      #pragma unroll
      for (int nt = 1; nt < 8; ++nt) m = fmaxf(m, s[mt][nt][reg]);
      #pragma unroll
      for (int off = 8; off >= 1; off >>= 1) m = fmaxf(m, __shfl_xor(m, off));
      float sum = 0.f;
      #pragma unroll
      for (int nt = 0; nt < 8; ++nt) {
        float e = __expf(s[mt][nt][reg] - m);
        s[mt][nt][reg] = e;
        sum += e;
      }
      #pragma unroll
      for (int off = 8; off >= 1; off >>= 1) sum += __shfl_xor(sum, off);
      float inv = 1.f / sum;
      int r = mt * 16 + quad * 4 + reg;
      #pragma unroll
      for (int nt = 0; nt < 8; ++nt)
        Pw[r * STRP2 + nt * 16 + l16] = __float2bfloat16(s[mt][nt][reg] * inv);
    }

  // ---- O = P V (K=128 -> 4 k-steps); V^T B-frags direct from global
  f32x4 o[2][2];
  o[0][0] = f32x4{0.f,0.f,0.f,0.f}; o[0][1] = f32x4{0.f,0.f,0.f,0.f};
  o[1][0] = f32x4{0.f,0.f,0.f,0.f}; o[1][1] = f32x4{0.f,0.f,0.f,0.f};
  #pragma unroll
  for (int ks = 0; ks < 4; ++ks) {
    bf16x8 bv0 = frag_at(VTh + (l16) * F_SZ      + ks * 32 + quad * 8);
    bf16x8 bv1 = frag_at(VTh + (16 + l16) * F_SZ + ks * 32 + quad * 8);
    #pragma unroll
    for (int mt = 0; mt < 2; ++mt) {
      bf16x8 ap = *reinterpret_cast<const bf16x8*>(
          Pw + (mt * 16 + l16) * STRP2 + ks * 32 + quad * 8);
      o[mt][0] = __builtin_amdgcn_mfma_f32_16x16x32_bf16(ap, bv0, o[mt][0], 0, 0, 0);
      o[mt][1] = __builtin_amdgcn_mfma_f32_16x16x32_bf16(ap, bv1, o[mt][1], 0, 0, 0);
    }
  }

  // ---- epilogue: + residual, relu (NaN-propagating), fp32 store
  #pragma unroll
  for (int mt = 0; mt < 2; ++mt)
    #pragma unroll
    for (int nt = 0; nt < 2; ++nt)
      #pragma unroll
      for (int reg = 0; reg < 4; ++reg) {
        int f = fw + mt * 16 + quad * 4 + reg;
        size_t idx = (rowbase + f) * E_SZ + hcol + nt * 16 + l16;
        float v = o[mt][nt][reg] + (float)Ro[idx];
        out[idx] = (v < 0.f) ? 0.f : v;
      }
}

// ---------------------------------------------------------------------------
extern "C" void kernel_launch(void* const* d_in, const int* in_sizes, int n_in,
                              void* d_out, int out_size, void* d_ws, size_t ws_size,
                              hipStream_t stream) {
  const float* X  = (const float*)d_in[0];
  const float* Wq = (const float*)d_in[1];
  const float* Wk = (const float*)d_in[2];
  const float* Wv = (const float*)d_in[3];
  const float* Wr = (const float*)d_in[4];
  float* out = (float*)d_out;

  char* ws = (char*)d_ws;
  const size_t WT_BYTES  = (size_t)4 * E_SZ * E_SZ * 2;           // 512 KB
  const size_t MAT_BYTES = (size_t)B_SZ * F_SZ * E_SZ * 2;        // 64 MB

  __hip_bfloat16* WT = (__hip_bfloat16*)ws;
  __hip_bfloat16* Qo = (__hip_bfloat16*)(ws + WT_BYTES);
  __hip_bfloat16* Ko = (__hip_bfloat16*)(ws + WT_BYTES + MAT_BYTES);
  __hip_bfloat16* Ro = (__hip_bfloat16*)(ws + WT_BYTES + 2 * MAT_BYTES);
  __hip_bfloat16* VT = (__hip_bfloat16*)(ws + WT_BYTES + 3 * MAT_BYTES);

  (void)hipGetLastError();  // clear stale error state
  transpose_weights<<<64, 256, 0, stream>>>(Wq, Wk, Wv, Wr, WT);
  gemm_qkvr<<<B_SZ * 8, 256, 0, stream>>>(X, WT, Qo, Ko, Ro, VT);
  attn<<<B_SZ * H_NUM, 256, 0, stream>>>(Qo, Ko, Ro, VT, out);

  // Launch-failure exfiltration (no-op when launches succeed).
  hipError_t err = hipGetLastError();
  if (err != hipSuccess) {
    hipMemsetAsync(d_out, 0x7F, 1024, stream);
  }
}